// Round 6
// baseline (109.175 us; speedup 1.0000x reference)
//
#include <hip/hip_runtime.h>

#define Hd 128
#define Wd 128
#define Cd 64
#define COd 64
#define Bd 4
#define HWd (Hd*Wd)

typedef __attribute__((ext_vector_type(8))) short  short8;
typedef __attribute__((ext_vector_type(4))) float  f32x4;

// Static device scratch.
__device__ __align__(16) short g_wbf[COd*576];                   // bf16 W[co][k], k=t*64+c
__device__ float4 g_offs[Bd*HWd];                                // (off0, off1, s1, s2)
__device__ __align__(16) unsigned short g_xt[(size_t)Bd*HWd*Cd]; // bf16 NHWC x

static __device__ __forceinline__ unsigned short f2bf(float v) {
    unsigned u = __float_as_uint(v);
    u += 0x7FFFu + ((u >> 16) & 1u);   // RNE
    return (unsigned short)(u >> 16);
}
static __device__ __forceinline__ float bflo(unsigned u) { return __uint_as_float(u << 16); }
static __device__ __forceinline__ float bfhi(unsigned u) { return __uint_as_float(u & 0xFFFF0000u); }
static __device__ __forceinline__ unsigned cvtpk(float lo, float hi) {
    unsigned r;
    asm("v_cvt_pk_bf16_f32 %0, %1, %2" : "=v"(r) : "v"(lo), "v"(hi));
    return r;
}

// One prep kernel: [0,512) NHWC repack ; [512,656) W->bf16.
__global__ __launch_bounds__(256) void k_prep(const float* __restrict__ x,
                                              const float* __restrict__ weight) {
    int bid = blockIdx.x;
    if (bid < 512) {
        int b = bid >> 7, y = bid & 127;
        int px = threadIdx.x & 127;
        int h  = threadIdx.x >> 7;
        const float* xb = x + (size_t)b*Cd*HWd + y*Wd + px;
        unsigned short* ob = g_xt + ((size_t)(b*HWd) + y*Wd + px)*Cd + h*32;
        #pragma unroll
        for (int oct = 0; oct < 4; ++oct) {
            unsigned pk[4];
            #pragma unroll
            for (int e = 0; e < 4; ++e) {
                float v0 = xb[(size_t)(h*32 + oct*8 + 2*e    )*HWd];
                float v1 = xb[(size_t)(h*32 + oct*8 + 2*e + 1)*HWd];
                pk[e] = (unsigned)f2bf(v0) | ((unsigned)f2bf(v1) << 16);
            }
            *(uint4*)(ob + oct*8) = make_uint4(pk[0], pk[1], pk[2], pk[3]);
        }
    } else {
        int g = (bid - 512)*256 + threadIdx.x;     // 64*576
        if (g < COd*576) {
            int co = g / 576, k = g % 576;
            int t = k >> 6, c = k & 63;            // k = t*64 + c
            g_wbf[g] = (short)f2bf(weight[(co*Cd + c)*9 + t]);
        }
    }
}

// Offsets conv (proven round-3 form): reads bf16 NHWC, wave-uniform weight idx.
__global__ __launch_bounds__(256) void k_offsets(const float* __restrict__ w_off,
                                                 const float* __restrict__ b_off) {
    __shared__ float red[4][128];
    int gid = blockIdx.x;               // 512 = b*128 + i
    int b = gid >> 7, i = gid & 127;
    int j = threadIdx.x & 127;
    int h = threadIdx.x >> 7;           // 32-channel half (wave-uniform)
    float a0 = 0.f, a1 = 0.f, a2 = 0.f, a3 = 0.f;
    const unsigned short* xb = g_xt + (size_t)b*HWd*Cd;
    #pragma unroll
    for (int dy = -1; dy <= 1; ++dy) {
        int yy = i + dy;
        if (yy < 0 || yy > 127) continue;
        #pragma unroll
        for (int dx = -1; dx <= 1; ++dx) {
            int xx = j + dx;
            if (xx < 0 || xx > 127) continue;
            int t = (dy + 1)*3 + (dx + 1);
            const unsigned short* p = xb + (size_t)(yy*Wd + xx)*Cd + h*32;
            #pragma unroll
            for (int oct = 0; oct < 4; ++oct) {
                uint4 u = *(const uint4*)(p + oct*8);
                unsigned aa[4] = {u.x, u.y, u.z, u.w};
                #pragma unroll
                for (int e = 0; e < 4; ++e) {
                    int c = h*32 + oct*8 + 2*e;
                    float v0 = bflo(aa[e]), v1 = bfhi(aa[e]);
                    a0 = fmaf(v0, w_off[(0*Cd + c)*9 + t], a0);
                    a0 = fmaf(v1, w_off[(0*Cd + c + 1)*9 + t], a0);
                    a1 = fmaf(v0, w_off[(1*Cd + c)*9 + t], a1);
                    a1 = fmaf(v1, w_off[(1*Cd + c + 1)*9 + t], a1);
                    a2 = fmaf(v0, w_off[(2*Cd + c)*9 + t], a2);
                    a2 = fmaf(v1, w_off[(2*Cd + c + 1)*9 + t], a2);
                    a3 = fmaf(v0, w_off[(3*Cd + c)*9 + t], a3);
                    a3 = fmaf(v1, w_off[(3*Cd + c + 1)*9 + t], a3);
                }
            }
        }
    }
    if (h == 1) { red[0][j] = a0; red[1][j] = a1; red[2][j] = a2; red[3][j] = a3; }
    __syncthreads();
    if (h == 0) {
        a0 += red[0][j] + b_off[0];
        a1 += red[1][j] + b_off[1];
        float s1 = fmaxf(a2 + red[2][j] + b_off[2], 0.f) + 1.f;
        float s2 = fmaxf(a3 + red[3][j] + b_off[3], 0.f) + 1.f;
        g_offs[(b*Hd + i)*Wd + j] = make_float4(a0, a1, s1, s2);
    }
}

// LDS-free deform: lane (pc,q) gathers its own B-fragment; wave = 16px x 64co.
__global__ __launch_bounds__(256, 4) void k_deform(const float* __restrict__ bias,
                                                   float* __restrict__ out) {
    int gid = blockIdx.x;               // 1024 = b*256 + i*2 + jh
    int b  = gid >> 8;
    int r  = gid & 255;
    int i  = r >> 1;
    int j0 = (r & 1) << 6;
    int w  = threadIdx.x >> 6;
    int l  = threadIdx.x & 63;
    int pc = l & 15, q = l >> 4;
    int j  = j0 + w*16 + pc;

    const unsigned short* xb = g_xt + (size_t)b*HWd*Cd;
    float4 o4 = g_offs[(b*Hd + i)*Wd + j];
    float off0 = o4.x, off1 = o4.y, s1 = o4.z, s2 = o4.w;

    f32x4 acc[4];
    #pragma unroll
    for (int cg = 0; cg < 4; ++cg) acc[cg] = (f32x4){0.f, 0.f, 0.f, 0.f};

    const short* wbase = g_wbf + pc*576 + q*8;   // + cg*16*576 + ks*32

    #pragma unroll 3
    for (int t = 0; t < 9; ++t) {
        float ys = (float)(i - 1) + (float)(t/3 - 1)*s1 + off0;
        float xs = (float)(j - 1) + (float)(t%3 - 1)*s2 + off1;
        float y0f = floorf(ys), x0f = floorf(xs);
        float wy = ys - y0f, wx = xs - x0f;
        float vy0 = (y0f >=  0.f && y0f <= 127.f) ? 1.f : 0.f;
        float vy1 = (y0f >= -1.f && y0f <= 126.f) ? 1.f : 0.f;
        float vx0 = (x0f >=  0.f && x0f <= 127.f) ? 1.f : 0.f;
        float vx1 = (x0f >= -1.f && x0f <= 126.f) ? 1.f : 0.f;
        float w00 = (1.f-wy)*(1.f-wx)*vy0*vx0, w01 = (1.f-wy)*wx*vy0*vx1;
        float w10 = wy*(1.f-wx)*vy1*vx0,       w11 = wy*wx*vy1*vx1;
        int iy0 = min(max((int)y0f,     0), 127), iy1 = min(max((int)y0f + 1, 0), 127);
        int ix0 = min(max((int)x0f,     0), 127), ix1 = min(max((int)x0f + 1, 0), 127);
        const unsigned short* p00 = xb + (size_t)(iy0*Wd + ix0)*Cd + q*8;
        const unsigned short* p01 = xb + (size_t)(iy0*Wd + ix1)*Cd + q*8;
        const unsigned short* p10 = xb + (size_t)(iy1*Wd + ix0)*Cd + q*8;
        const unsigned short* p11 = xb + (size_t)(iy1*Wd + ix1)*Cd + q*8;

        // ---- even K-step: channels q*8..q*8+7 ----
        uint4 u00 = *(const uint4*)p00, u01 = *(const uint4*)p01;
        uint4 u10 = *(const uint4*)p10, u11 = *(const uint4*)p11;
        // ---- odd K-step: channels q*8+32.. (same lines, +64B) ----
        uint4 v00 = *(const uint4*)(p00 + 32), v01 = *(const uint4*)(p01 + 32);
        uint4 v10 = *(const uint4*)(p10 + 32), v11 = *(const uint4*)(p11 + 32);

        unsigned a00[4] = {u00.x,u00.y,u00.z,u00.w}, a01[4] = {u01.x,u01.y,u01.z,u01.w};
        unsigned a10[4] = {u10.x,u10.y,u10.z,u10.w}, a11[4] = {u11.x,u11.y,u11.z,u11.w};
        unsigned c00[4] = {v00.x,v00.y,v00.z,v00.w}, c01[4] = {v01.x,v01.y,v01.z,v01.w};
        unsigned c10[4] = {v10.x,v10.y,v10.z,v10.w}, c11[4] = {v11.x,v11.y,v11.z,v11.w};

        unsigned pe[4], po[4];
        #pragma unroll
        for (int e = 0; e < 4; ++e) {
            float vlo = fmaf(w00, bflo(a00[e]), fmaf(w01, bflo(a01[e]),
                        fmaf(w10, bflo(a10[e]), w11*bflo(a11[e]))));
            float vhi = fmaf(w00, bfhi(a00[e]), fmaf(w01, bfhi(a01[e]),
                        fmaf(w10, bfhi(a10[e]), w11*bfhi(a11[e]))));
            pe[e] = cvtpk(vlo, vhi);
            float wlo = fmaf(w00, bflo(c00[e]), fmaf(w01, bflo(c01[e]),
                        fmaf(w10, bflo(c10[e]), w11*bflo(c11[e]))));
            float whi = fmaf(w00, bfhi(c00[e]), fmaf(w01, bfhi(c01[e]),
                        fmaf(w10, bfhi(c10[e]), w11*bfhi(c11[e]))));
            po[e] = cvtpk(wlo, whi);
        }
        uint4 beu = make_uint4(pe[0], pe[1], pe[2], pe[3]);
        uint4 bou = make_uint4(po[0], po[1], po[2], po[3]);
        short8 be = *(short8*)&beu;
        short8 bo = *(short8*)&bou;

        const int ks0 = 2*t;
        #pragma unroll
        for (int cg = 0; cg < 4; ++cg) {
            short8 av = *(const short8*)(wbase + (size_t)cg*16*576 + ks0*32);
            acc[cg] = __builtin_amdgcn_mfma_f32_16x16x32_bf16(av, be, acc[cg], 0, 0, 0);
        }
        #pragma unroll
        for (int cg = 0; cg < 4; ++cg) {
            short8 av = *(const short8*)(wbase + (size_t)cg*16*576 + ks0*32 + 32);
            acc[cg] = __builtin_amdgcn_mfma_f32_16x16x32_bf16(av, bo, acc[cg], 0, 0, 0);
        }
    }

    // D: col = pc (=px), row = q*4 + rr (+cg*16) -> co
    #pragma unroll
    for (int cg = 0; cg < 4; ++cg) {
        float4 bv = *(const float4*)(bias + cg*16 + q*4);
        float bb[4] = {bv.x, bv.y, bv.z, bv.w};
        #pragma unroll
        for (int rr = 0; rr < 4; ++rr) {
            int co = cg*16 + q*4 + rr;
            out[((size_t)(b*COd + co)*Hd + i)*Wd + j] = acc[cg][rr] + bb[rr];
        }
    }
}

extern "C" void kernel_launch(void* const* d_in, const int* in_sizes, int n_in,
                              void* d_out, int out_size, void* d_ws, size_t ws_size,
                              hipStream_t stream) {
    const float* x      = (const float*)d_in[0];
    const float* w_off  = (const float*)d_in[1];
    const float* b_off  = (const float*)d_in[2];
    const float* weight = (const float*)d_in[3];
    const float* bias   = (const float*)d_in[4];
    float* out = (float*)d_out;

    hipLaunchKernelGGL(k_prep,    dim3(656),  dim3(256), 0, stream, x, weight);
    hipLaunchKernelGGL(k_offsets, dim3(512),  dim3(256), 0, stream, w_off, b_off);
    hipLaunchKernelGGL(k_deform,  dim3(1024), dim3(256), 0, stream, bias, out);
}